// Round 3
// baseline (46.110 us; speedup 1.0000x reference)
//
#include <hip/hip_runtime.h>

#define HH 1024
#define WW 1024
#define BS 16
#define ROWS 16
#define NPIX ((size_t)HH * (size_t)WW)

typedef float v4f __attribute__((ext_vector_type(4)));

__device__ __forceinline__ float max5(float a, float b, float c, float d, float e) {
    return fmaxf(fmaxf(fmaxf(a, b), fmaxf(c, d)), e);
}

__device__ __forceinline__ float4 ldrow4(const float* __restrict__ x, int row, int col) {
    if ((unsigned)row < (unsigned)HH)
        return *reinterpret_cast<const float4*>(x + (size_t)row * WW + col);
    return make_float4(0.f, 0.f, 0.f, 0.f);
}

__device__ __forceinline__ float2 ldhalo2(const float* __restrict__ x, int row, int col) {
    if ((unsigned)row < (unsigned)HH && (unsigned)col < (unsigned)WW)
        return *reinterpret_cast<const float2*>(x + (size_t)row * WW + col);
    return make_float2(0.f, 0.f);
}

// Non-temporal 16B store: output is 192 MB of write-once data — keep it out of L2.
__device__ __forceinline__ void st_nt4(float* p, float a, float b, float c, float d) {
    v4f v = {a, b, c, d};
    __builtin_nontemporal_store(v, reinterpret_cast<v4f*>(p));
}

__global__ __launch_bounds__(256) void nms_head_kernel(
    const float* __restrict__ in,      // (bs,1,H,W)
    const float* __restrict__ scale,   // (bs,)
    const float* __restrict__ center,  // (bs,2)
    float* __restrict__ out)           // masked_world (bs,2,H,W) ++ mask (bs,H,W)
{
    const int tid  = threadIdx.x;
    const int lane = tid & 63;
    const int wv   = tid >> 6;          // wave id 0..3, each owns a 256-col strip
    const int c0   = wv * 256;
    const int col  = c0 + lane * 4;     // 4 consecutive columns per lane
    const int r0   = blockIdx.x * ROWS;
    const int b    = blockIdx.y;

    const float s  = scale[b];
    const float cx = center[2 * b];
    const float cy = center[2 * b + 1];

    const float* xin = in + (size_t)b * NPIX;
    float* out_wx = out + (size_t)b * 2 * NPIX;
    float* out_wy = out_wx + NPIX;
    float* out_m  = out + (size_t)BS * 2 * NPIX + (size_t)b * NPIX;

    // Wave-edge halo: lane 0 maintains cols c0-2,c0-1 ; lane 63 cols c0+256,c0+257
    const bool hA = (lane == 0);
    const bool hB = (lane == 63);
    const bool halo = hA || hB;
    const int hcol = hA ? (c0 - 2) : (c0 + 256);

    // Vertical 5-tap sliding windows (zero pad == reference constant_values=0,
    // valid since all inputs are >= 0)
    float4 va = ldrow4(xin, r0 - 2, col);
    float4 vb = ldrow4(xin, r0 - 1, col);
    float4 vc = ldrow4(xin, r0 + 0, col);
    float4 vd = ldrow4(xin, r0 + 1, col);
    float2 ga = make_float2(0.f, 0.f), gb = ga, gc = ga, gd = ga;
    if (halo) {
        ga = ldhalo2(xin, r0 - 2, hcol);
        gb = ldhalo2(xin, r0 - 1, hcol);
        gc = ldhalo2(xin, r0 + 0, hcol);
        gd = ldhalo2(xin, r0 + 1, hcol);
    }

    const float wxx = ((float)(col + 0) - 512.0f) * s + cx;
    const float wxy = ((float)(col + 1) - 512.0f) * s + cx;
    const float wxz = ((float)(col + 2) - 512.0f) * s + cx;
    const float wxw = ((float)(col + 3) - 512.0f) * s + cx;

    for (int y = r0; y < r0 + ROWS; ++y) {
        float4 ve = ldrow4(xin, y + 2, col);
        float2 ge = halo ? ldhalo2(xin, y + 2, hcol) : make_float2(0.f, 0.f);

        float4 vm;
        vm.x = max5(va.x, vb.x, vc.x, vd.x, ve.x);
        vm.y = max5(va.y, vb.y, vc.y, vd.y, ve.y);
        vm.z = max5(va.z, vb.z, vc.z, vd.z, ve.z);
        vm.w = max5(va.w, vb.w, vc.w, vd.w, ve.w);
        float gmx = max5(ga.x, gb.x, gc.x, gd.x, ge.x);
        float gmy = max5(ga.y, gb.y, gc.y, gd.y, ge.y);

        // Neighbor exchange: 2 cols from left lane, 2 from right lane
        float Lx = __shfl_up(vm.z, 1);
        float Ly = __shfl_up(vm.w, 1);
        float Rx = __shfl_down(vm.x, 1);
        float Ry = __shfl_down(vm.y, 1);
        if (hA) { Lx = gmx; Ly = gmy; }
        if (hB) { Rx = gmx; Ry = gmy; }

        float h0 = max5(Lx, Ly, vm.x, vm.y, vm.z);
        float h1 = max5(Ly, vm.x, vm.y, vm.z, vm.w);
        float h2 = max5(vm.x, vm.y, vm.z, vm.w, Rx);
        float h3 = max5(vm.y, vm.z, vm.w, Rx, Ry);

        const bool m0 = (h0 > 1e-5f) && (h0 == vc.x);
        const bool m1 = (h1 > 1e-5f) && (h1 == vc.y);
        const bool m2 = (h2 > 1e-5f) && (h2 == vc.z);
        const bool m3 = (h3 > 1e-5f) && (h3 == vc.w);

        const float wy = (512.0f - (float)y) * s + cy;
        const size_t off = (size_t)y * WW + col;

        st_nt4(out_wx + off, m0 ? wxx : 0.f, m1 ? wxy : 0.f,
                             m2 ? wxz : 0.f, m3 ? wxw : 0.f);
        st_nt4(out_wy + off, m0 ? wy : 0.f, m1 ? wy : 0.f,
                             m2 ? wy : 0.f, m3 ? wy : 0.f);
        st_nt4(out_m  + off, m0 ? 1.f : 0.f, m1 ? 1.f : 0.f,
                             m2 ? 1.f : 0.f, m3 ? 1.f : 0.f);

        va = vb; vb = vc; vc = vd; vd = ve;
        ga = gb; gb = gc; gc = gd; gd = ge;
    }
}

extern "C" void kernel_launch(void* const* d_in, const int* in_sizes, int n_in,
                              void* d_out, int out_size, void* d_ws, size_t ws_size,
                              hipStream_t stream) {
    const float* in     = (const float*)d_in[0];
    const float* scale  = (const float*)d_in[1];
    const float* center = (const float*)d_in[2];
    float* out = (float*)d_out;

    dim3 grid(HH / ROWS, BS);
    nms_head_kernel<<<grid, dim3(256), 0, stream>>>(in, scale, center, out);
}

// Round 4
// 45.451 us; speedup vs baseline: 1.0145x; 1.0145x over previous
//
#include <hip/hip_runtime.h>

#define HH 1024
#define WW 1024
#define BS 16
#define ROWS 8
#define NPIX ((size_t)HH * (size_t)WW)

__device__ __forceinline__ float max5(float a, float b, float c, float d, float e) {
    return fmaxf(fmaxf(fmaxf(a, b), fmaxf(c, d)), e);
}

__device__ __forceinline__ float4 ldrow4(const float* __restrict__ x, int row, int col) {
    if ((unsigned)row < (unsigned)HH)
        return *reinterpret_cast<const float4*>(x + (size_t)row * WW + col);
    return make_float4(0.f, 0.f, 0.f, 0.f);
}

__device__ __forceinline__ float2 ldhalo2(const float* __restrict__ x, int row, int col) {
    if ((unsigned)row < (unsigned)HH && (unsigned)col < (unsigned)WW)
        return *reinterpret_cast<const float2*>(x + (size_t)row * WW + col);
    return make_float2(0.f, 0.f);
}

__global__ __launch_bounds__(256) void nms_head_kernel(
    const float* __restrict__ in,      // (bs,1,H,W)
    const float* __restrict__ scale,   // (bs,)
    const float* __restrict__ center,  // (bs,2)
    float* __restrict__ out)           // masked_world (bs,2,H,W) ++ mask (bs,H,W)
{
    const int tid  = threadIdx.x;
    const int lane = tid & 63;
    const int wv   = tid >> 6;          // wave id 0..3, each owns a 256-col strip
    const int c0   = wv * 256;
    const int col  = c0 + lane * 4;     // 4 consecutive columns per lane
    const int r0   = blockIdx.x * ROWS;
    const int b    = blockIdx.y;

    const float s  = scale[b];
    const float cx = center[2 * b];
    const float cy = center[2 * b + 1];

    const float* xin = in + (size_t)b * NPIX;
    float* out_wx = out + (size_t)b * 2 * NPIX;
    float* out_wy = out_wx + NPIX;
    float* out_m  = out + (size_t)BS * 2 * NPIX + (size_t)b * NPIX;

    // Wave-edge halo: lane 0 maintains cols c0-2,c0-1 ; lane 63 cols c0+256,c0+257
    const bool hA = (lane == 0);
    const bool hB = (lane == 63);
    const bool halo = hA || hB;
    const int hcol = hA ? (c0 - 2) : (c0 + 256);

    // Vertical 5-tap sliding windows (zero pad == reference constant_values=0,
    // valid since all inputs are >= 0)
    float4 va = ldrow4(xin, r0 - 2, col);
    float4 vb = ldrow4(xin, r0 - 1, col);
    float4 vc = ldrow4(xin, r0 + 0, col);
    float4 vd = ldrow4(xin, r0 + 1, col);
    float2 ga = make_float2(0.f, 0.f), gb = ga, gc = ga, gd = ga;
    if (halo) {
        ga = ldhalo2(xin, r0 - 2, hcol);
        gb = ldhalo2(xin, r0 - 1, hcol);
        gc = ldhalo2(xin, r0 + 0, hcol);
        gd = ldhalo2(xin, r0 + 1, hcol);
    }

    const float wxx = ((float)(col + 0) - 512.0f) * s + cx;
    const float wxy = ((float)(col + 1) - 512.0f) * s + cx;
    const float wxz = ((float)(col + 2) - 512.0f) * s + cx;
    const float wxw = ((float)(col + 3) - 512.0f) * s + cx;

    for (int y = r0; y < r0 + ROWS; ++y) {
        float4 ve = ldrow4(xin, y + 2, col);
        float2 ge = halo ? ldhalo2(xin, y + 2, hcol) : make_float2(0.f, 0.f);

        float4 vm;
        vm.x = max5(va.x, vb.x, vc.x, vd.x, ve.x);
        vm.y = max5(va.y, vb.y, vc.y, vd.y, ve.y);
        vm.z = max5(va.z, vb.z, vc.z, vd.z, ve.z);
        vm.w = max5(va.w, vb.w, vc.w, vd.w, ve.w);
        float gmx = max5(ga.x, gb.x, gc.x, gd.x, ge.x);
        float gmy = max5(ga.y, gb.y, gc.y, gd.y, ge.y);

        // Neighbor exchange: 2 cols from left lane, 2 from right lane
        float Lx = __shfl_up(vm.z, 1);
        float Ly = __shfl_up(vm.w, 1);
        float Rx = __shfl_down(vm.x, 1);
        float Ry = __shfl_down(vm.y, 1);
        if (hA) { Lx = gmx; Ly = gmy; }
        if (hB) { Rx = gmx; Ry = gmy; }

        float h0 = max5(Lx, Ly, vm.x, vm.y, vm.z);
        float h1 = max5(Ly, vm.x, vm.y, vm.z, vm.w);
        float h2 = max5(vm.x, vm.y, vm.z, vm.w, Rx);
        float h3 = max5(vm.y, vm.z, vm.w, Rx, Ry);

        const bool m0 = (h0 > 1e-5f) && (h0 == vc.x);
        const bool m1 = (h1 > 1e-5f) && (h1 == vc.y);
        const bool m2 = (h2 > 1e-5f) && (h2 == vc.z);
        const bool m3 = (h3 > 1e-5f) && (h3 == vc.w);

        const float wy = (512.0f - (float)y) * s + cy;
        const size_t off = (size_t)y * WW + col;

        float4 owx = make_float4(m0 ? wxx : 0.f, m1 ? wxy : 0.f,
                                 m2 ? wxz : 0.f, m3 ? wxw : 0.f);
        float4 owy = make_float4(m0 ? wy : 0.f, m1 ? wy : 0.f,
                                 m2 ? wy : 0.f, m3 ? wy : 0.f);
        float4 om  = make_float4(m0 ? 1.f : 0.f, m1 ? 1.f : 0.f,
                                 m2 ? 1.f : 0.f, m3 ? 1.f : 0.f);

        *reinterpret_cast<float4*>(out_wx + off) = owx;
        *reinterpret_cast<float4*>(out_wy + off) = owy;
        *reinterpret_cast<float4*>(out_m  + off) = om;

        va = vb; vb = vc; vc = vd; vd = ve;
        ga = gb; gb = gc; gc = gd; gd = ge;
    }
}

extern "C" void kernel_launch(void* const* d_in, const int* in_sizes, int n_in,
                              void* d_out, int out_size, void* d_ws, size_t ws_size,
                              hipStream_t stream) {
    const float* in     = (const float*)d_in[0];
    const float* scale  = (const float*)d_in[1];
    const float* center = (const float*)d_in[2];
    float* out = (float*)d_out;

    dim3 grid(HH / ROWS, BS);
    nms_head_kernel<<<grid, dim3(256), 0, stream>>>(in, scale, center, out);
}

// Round 5
// 43.742 us; speedup vs baseline: 1.0541x; 1.0391x over previous
//
#include <hip/hip_runtime.h>

#define HH 1024
#define WW 1024
#define BS 16
#define ROWS 16
#define NPIX ((size_t)HH * (size_t)WW)

__device__ __forceinline__ float max5(float a, float b, float c, float d, float e) {
    return fmaxf(fmaxf(fmaxf(a, b), fmaxf(c, d)), e);
}

__device__ __forceinline__ float4 ldrow4(const float* __restrict__ x, int row, int col) {
    if ((unsigned)row < (unsigned)HH)
        return *reinterpret_cast<const float4*>(x + (size_t)row * WW + col);
    return make_float4(0.f, 0.f, 0.f, 0.f);
}

__device__ __forceinline__ float2 ldhalo2(const float* __restrict__ x, int row, int col) {
    if ((unsigned)row < (unsigned)HH && (unsigned)col < (unsigned)WW)
        return *reinterpret_cast<const float2*>(x + (size_t)row * WW + col);
    return make_float2(0.f, 0.f);
}

__global__ __launch_bounds__(256) void nms_head_kernel(
    const float* __restrict__ in,      // (bs,1,H,W)
    const float* __restrict__ scale,   // (bs,)
    const float* __restrict__ center,  // (bs,2)
    float* __restrict__ out)           // masked_world (bs,2,H,W) ++ mask (bs,H,W)
{
    const int tid  = threadIdx.x;
    const int lane = tid & 63;
    const int wv   = tid >> 6;          // wave id 0..3, each owns a 256-col strip
    const int c0   = wv * 256;
    const int col  = c0 + lane * 4;     // 4 consecutive columns per lane
    const int r0   = blockIdx.x * ROWS;
    const int b    = blockIdx.y;

    const float s  = scale[b];
    const float cx = center[2 * b];
    const float cy = center[2 * b + 1];

    const float* xin = in + (size_t)b * NPIX;
    float* out_wx = out + (size_t)b * 2 * NPIX;
    float* out_wy = out_wx + NPIX;
    float* out_m  = out + (size_t)BS * 2 * NPIX + (size_t)b * NPIX;

    // Wave-edge halo: lane 0 maintains cols c0-2,c0-1 ; lane 63 cols c0+256,c0+257
    const bool hA = (lane == 0);
    const bool hB = (lane == 63);
    const bool halo = hA || hB;
    const int hcol = hA ? (c0 - 2) : (c0 + 256);

    // Vertical 5-tap sliding windows (zero pad == reference constant_values=0,
    // valid since all inputs are >= 0)
    float4 va = ldrow4(xin, r0 - 2, col);
    float4 vb = ldrow4(xin, r0 - 1, col);
    float4 vc = ldrow4(xin, r0 + 0, col);
    float4 vd = ldrow4(xin, r0 + 1, col);
    float2 ga = make_float2(0.f, 0.f), gb = ga, gc = ga, gd = ga;
    if (halo) {
        ga = ldhalo2(xin, r0 - 2, hcol);
        gb = ldhalo2(xin, r0 - 1, hcol);
        gc = ldhalo2(xin, r0 + 0, hcol);
        gd = ldhalo2(xin, r0 + 1, hcol);
    }

    const float wxx = ((float)(col + 0) - 512.0f) * s + cx;
    const float wxy = ((float)(col + 1) - 512.0f) * s + cx;
    const float wxz = ((float)(col + 2) - 512.0f) * s + cx;
    const float wxw = ((float)(col + 3) - 512.0f) * s + cx;

    for (int y = r0; y < r0 + ROWS; ++y) {
        float4 ve = ldrow4(xin, y + 2, col);
        float2 ge = halo ? ldhalo2(xin, y + 2, hcol) : make_float2(0.f, 0.f);

        float4 vm;
        vm.x = max5(va.x, vb.x, vc.x, vd.x, ve.x);
        vm.y = max5(va.y, vb.y, vc.y, vd.y, ve.y);
        vm.z = max5(va.z, vb.z, vc.z, vd.z, ve.z);
        vm.w = max5(va.w, vb.w, vc.w, vd.w, ve.w);
        float gmx = max5(ga.x, gb.x, gc.x, gd.x, ge.x);
        float gmy = max5(ga.y, gb.y, gc.y, gd.y, ge.y);

        // Neighbor exchange: 2 cols from left lane, 2 from right lane
        float Lx = __shfl_up(vm.z, 1);
        float Ly = __shfl_up(vm.w, 1);
        float Rx = __shfl_down(vm.x, 1);
        float Ry = __shfl_down(vm.y, 1);
        if (hA) { Lx = gmx; Ly = gmy; }
        if (hB) { Rx = gmx; Ry = gmy; }

        float h0 = max5(Lx, Ly, vm.x, vm.y, vm.z);
        float h1 = max5(Ly, vm.x, vm.y, vm.z, vm.w);
        float h2 = max5(vm.x, vm.y, vm.z, vm.w, Rx);
        float h3 = max5(vm.y, vm.z, vm.w, Rx, Ry);

        const bool m0 = (h0 > 1e-5f) && (h0 == vc.x);
        const bool m1 = (h1 > 1e-5f) && (h1 == vc.y);
        const bool m2 = (h2 > 1e-5f) && (h2 == vc.z);
        const bool m3 = (h3 > 1e-5f) && (h3 == vc.w);

        const float wy = (512.0f - (float)y) * s + cy;
        const size_t off = (size_t)y * WW + col;

        float4 owx = make_float4(m0 ? wxx : 0.f, m1 ? wxy : 0.f,
                                 m2 ? wxz : 0.f, m3 ? wxw : 0.f);
        float4 owy = make_float4(m0 ? wy : 0.f, m1 ? wy : 0.f,
                                 m2 ? wy : 0.f, m3 ? wy : 0.f);
        float4 om  = make_float4(m0 ? 1.f : 0.f, m1 ? 1.f : 0.f,
                                 m2 ? 1.f : 0.f, m3 ? 1.f : 0.f);

        *reinterpret_cast<float4*>(out_wx + off) = owx;
        *reinterpret_cast<float4*>(out_wy + off) = owy;
        *reinterpret_cast<float4*>(out_m  + off) = om;

        va = vb; vb = vc; vc = vd; vd = ve;
        ga = gb; gb = gc; gc = gd; gd = ge;
    }
}

extern "C" void kernel_launch(void* const* d_in, const int* in_sizes, int n_in,
                              void* d_out, int out_size, void* d_ws, size_t ws_size,
                              hipStream_t stream) {
    const float* in     = (const float*)d_in[0];
    const float* scale  = (const float*)d_in[1];
    const float* center = (const float*)d_in[2];
    float* out = (float*)d_out;

    dim3 grid(HH / ROWS, BS);
    nms_head_kernel<<<grid, dim3(256), 0, stream>>>(in, scale, center, out);
}